// Round 1
// baseline (317.294 us; speedup 1.0000x reference)
//
#include <hip/hip_runtime.h>
#include <hip/hip_bf16.h>

#define VOCAB 50257
#define NUM_DIM 1024

// out[t, d] = weight[d, tok[t]] + bias[d]
// One block per token; 256 threads × 4 dims each = 1024 dims.
// Writes are float4-coalesced; weight reads are inherently scattered
// (column gather, stride VOCAB floats) — LLC absorbs repeats.
__global__ void __launch_bounds__(256) token_embed_kernel(
    const int* __restrict__ tokens,
    const float* __restrict__ weight,
    const float* __restrict__ bias,
    float* __restrict__ out,
    int n_tok)
{
    int t = blockIdx.x;
    if (t >= n_tok) return;
    int tok = tokens[t];  // uniform across block -> scalar load

    int d = threadIdx.x * 4;

    const float* __restrict__ wcol = weight + tok;
    float4 b4 = *reinterpret_cast<const float4*>(bias + d);

    // 4 independent scattered loads (each its own cache line)
    float w0 = wcol[(size_t)(d + 0) * VOCAB];
    float w1 = wcol[(size_t)(d + 1) * VOCAB];
    float w2 = wcol[(size_t)(d + 2) * VOCAB];
    float w3 = wcol[(size_t)(d + 3) * VOCAB];

    float4 o;
    o.x = w0 + b4.x;
    o.y = w1 + b4.y;
    o.z = w2 + b4.z;
    o.w = w3 + b4.w;

    *reinterpret_cast<float4*>(out + (size_t)t * NUM_DIM + d) = o;
}

extern "C" void kernel_launch(void* const* d_in, const int* in_sizes, int n_in,
                              void* d_out, int out_size, void* d_ws, size_t ws_size,
                              hipStream_t stream)
{
    const int*   tokens = (const int*)d_in[0];
    const float* weight = (const float*)d_in[1];
    const float* bias   = (const float*)d_in[2];
    float*       out    = (float*)d_out;

    int n_tok = in_sizes[0];  // BATCH * SEQ = 16384

    dim3 grid(n_tok);
    dim3 block(256);
    token_embed_kernel<<<grid, block, 0, stream>>>(tokens, weight, bias, out, n_tok);
}

// Round 2
// 179.802 us; speedup vs baseline: 1.7647x; 1.7647x over previous
//
#include <hip/hip_runtime.h>
#include <hip/hip_bf16.h>

#define VOCAB   50257
#define NUM_DIM 1024
#define DB 64      // dims per tile
#define VB 128     // vocab entries per tile
#define CAP 16     // bucket capacity per vocab entry

static_assert((VB & (VB - 1)) == 0, "VB must be power of 2");
static_assert((DB & (DB - 1)) == 0, "DB must be power of 2");

// ---------------- helper kernels ----------------

__global__ void __launch_bounds__(256) init_kernel(int* counts, int* n_ov) {
    int i = blockIdx.x * 256 + threadIdx.x;
    if (i < VOCAB) counts[i] = 0;
    if (i == 0) *n_ov = 0;
}

__global__ void __launch_bounds__(256) scatter_kernel(
    const int* __restrict__ tokens, int n_tok,
    int* counts, int* buckets, int* n_ov, int* ov_list)
{
    int i = blockIdx.x * 256 + threadIdx.x;
    if (i >= n_tok) return;
    int v = tokens[i];
    int slot = atomicAdd(&counts[v], 1);
    if (slot < CAP) buckets[v * CAP + slot] = i;
    else { int p = atomicAdd(n_ov, 1); ov_list[p] = i; }
}

// ---------------- main: stream weight once, scatter to output rows ----------------

__global__ void __launch_bounds__(256) embed_main(
    const float* __restrict__ weight, const float* __restrict__ bias,
    const int* __restrict__ counts, const int* __restrict__ buckets,
    float* __restrict__ out)
{
    __shared__ float tile[DB][VB + 1];     // +1 pad: column read -> 2-way bank (free)
    __shared__ unsigned list[VB * CAP];    // packed (t<<7 | vl)
    __shared__ int nlist;

    int tid = threadIdx.x;
    int v0 = blockIdx.x * VB;
    int d0 = blockIdx.y * DB;

    if (tid == 0) nlist = 0;

    // coalesced tile load: consecutive tid -> consecutive vocab index
    for (int idx = tid; idx < DB * VB; idx += 256) {
        int vl = idx & (VB - 1);
        int d  = idx >> 7;                 // VB == 128
        int v  = v0 + vl;
        tile[d][vl] = (v < VOCAB) ? weight[(size_t)(d0 + d) * VOCAB + v] : 0.f;
    }
    __syncthreads();

    // build compact token list for this vocab chunk
    for (int idx = tid; idx < VB * CAP; idx += 256) {
        int vl = idx / CAP;
        int slot = idx - vl * CAP;
        int v = v0 + vl;
        if (v < VOCAB) {
            int c = counts[v];
            if (c > CAP) c = CAP;
            if (slot < c) {
                int t = buckets[v * CAP + slot];
                int p = atomicAdd(&nlist, 1);
                list[p] = ((unsigned)t << 7) | (unsigned)vl;
            }
        }
    }
    __syncthreads();

    // write phase: wave = 64 lanes along d -> 256B contiguous store per token
    int d  = tid & (DB - 1);
    int tl = tid >> 6;                     // 0..3 (token slot within group of 4)
    float b = bias[d0 + d];
    int n = nlist;
    for (int i = tl; i < n; i += 4) {
        unsigned e = list[i];
        int vl = e & (VB - 1);
        int t  = e >> 7;
        out[(size_t)t * NUM_DIM + d0 + d] = tile[d][vl] + b;
    }
}

// ---------------- overflow fallback (naive column gather; n_ov == 0 in practice) --------

__global__ void __launch_bounds__(256) embed_overflow(
    const int* __restrict__ tokens, const float* __restrict__ weight,
    const float* __restrict__ bias, const int* __restrict__ n_ov,
    const int* __restrict__ ov_list, float* __restrict__ out)
{
    int n = *n_ov;
    for (int blk = blockIdx.x; blk < n; blk += gridDim.x) {
        int t = ov_list[blk];
        int v = tokens[t];
        int dd = threadIdx.x * 4;
        const float* wcol = weight + v;
        float4 b4 = *reinterpret_cast<const float4*>(bias + dd);
        float4 o;
        o.x = wcol[(size_t)(dd + 0) * VOCAB] + b4.x;
        o.y = wcol[(size_t)(dd + 1) * VOCAB] + b4.y;
        o.z = wcol[(size_t)(dd + 2) * VOCAB] + b4.z;
        o.w = wcol[(size_t)(dd + 3) * VOCAB] + b4.w;
        *reinterpret_cast<float4*>(out + (size_t)t * NUM_DIM + dd) = o;
    }
}

// ---------------- naive fallback if ws too small ----------------

__global__ void __launch_bounds__(256) token_embed_naive(
    const int* __restrict__ tokens, const float* __restrict__ weight,
    const float* __restrict__ bias, float* __restrict__ out, int n_tok)
{
    int t = blockIdx.x;
    if (t >= n_tok) return;
    int tok = tokens[t];
    int dd = threadIdx.x * 4;
    const float* wcol = weight + tok;
    float4 b4 = *reinterpret_cast<const float4*>(bias + dd);
    float4 o;
    o.x = wcol[(size_t)(dd + 0) * VOCAB] + b4.x;
    o.y = wcol[(size_t)(dd + 1) * VOCAB] + b4.y;
    o.z = wcol[(size_t)(dd + 2) * VOCAB] + b4.z;
    o.w = wcol[(size_t)(dd + 3) * VOCAB] + b4.w;
    *reinterpret_cast<float4*>(out + (size_t)t * NUM_DIM + dd) = o;
}

extern "C" void kernel_launch(void* const* d_in, const int* in_sizes, int n_in,
                              void* d_out, int out_size, void* d_ws, size_t ws_size,
                              hipStream_t stream)
{
    const int*   tokens = (const int*)d_in[0];
    const float* weight = (const float*)d_in[1];
    const float* bias   = (const float*)d_in[2];
    float*       out    = (float*)d_out;
    int n_tok = in_sizes[0];               // 16384

    // ws layout (ints): counts[VOCAB] | buckets[VOCAB*CAP] | n_ov[64] | ov_list[n_tok]
    size_t need_ints = (size_t)VOCAB + (size_t)VOCAB * CAP + 64 + (size_t)n_tok;
    if (ws_size < need_ints * sizeof(int)) {
        token_embed_naive<<<n_tok, 256, 0, stream>>>(tokens, weight, bias, out, n_tok);
        return;
    }

    int* counts  = (int*)d_ws;
    int* buckets = counts + VOCAB;
    int* n_ov    = buckets + (size_t)VOCAB * CAP;
    int* ov_list = n_ov + 64;

    init_kernel<<<(VOCAB + 255) / 256, 256, 0, stream>>>(counts, n_ov);
    scatter_kernel<<<(n_tok + 255) / 256, 256, 0, stream>>>(
        tokens, n_tok, counts, buckets, n_ov, ov_list);

    dim3 grid((VOCAB + VB - 1) / VB, NUM_DIM / DB);   // (393, 16)
    embed_main<<<grid, 256, 0, stream>>>(weight, bias, counts, buckets, out);

    embed_overflow<<<64, 256, 0, stream>>>(tokens, weight, bias, n_ov, ov_list, out);
}

// Round 3
// 73.660 us; speedup vs baseline: 4.3075x; 2.4410x over previous
//
#include <hip/hip_runtime.h>
#include <hip/hip_bf16.h>

#define VOCAB   50257
#define NUM_DIM 1024
#define VB 64                              // vocab entries per tile
#define DB 64                              // dims per tile
#define NVCH ((VOCAB + VB - 1) / VB)       // 786 vocab chunks
#define CLCAP 96                           // list capacity per chunk (mean ~21)

// ---------------- helpers ----------------

__global__ void __launch_bounds__(256) init_kernel(int* ccount, int* n_ov) {
    int i = blockIdx.x * 256 + threadIdx.x;
    if (i < NVCH) ccount[i] = 0;
    if (i == 0) *n_ov = 0;
}

__global__ void __launch_bounds__(256) scatter_kernel(
    const int* __restrict__ tokens, int n_tok,
    int* ccount, unsigned* clist, int* n_ov, int* ov_list)
{
    int i = blockIdx.x * 256 + threadIdx.x;
    if (i >= n_tok) return;
    int v = tokens[i];
    int ch = v >> 6;                                   // vocab chunk (VB=64)
    int slot = atomicAdd(&ccount[ch], 1);
    if (slot < CLCAP) clist[(size_t)ch * CLCAP + slot] = ((unsigned)i << 6) | (unsigned)(v & 63);
    else { int p = atomicAdd(n_ov, 1); ov_list[p] = i; }
}

// ---------------- main: stream weight once, scatter to output rows ----------------

__global__ void __launch_bounds__(256) embed_main(
    const float* __restrict__ weight, const float* __restrict__ bias,
    const int* __restrict__ ccount, const unsigned* __restrict__ clist,
    float* __restrict__ out)
{
    __shared__ float tile[DB][VB + 1];     // stride 65: column reads conflict-free
    __shared__ unsigned slist[CLCAP];
    __shared__ int snn;

    int tid = threadIdx.x;
    int cv = blockIdx.x;
    int v0 = cv * VB;
    int d0 = blockIdx.y * DB;

    if (tid == 0) {
        int c = ccount[cv];
        snn = c < CLCAP ? c : CLCAP;
    }
    if (tid < CLCAP) slist[tid] = clist[(size_t)cv * CLCAP + tid];

    // tile load: 64 rows x 16 float4-chunks; coalesced along vocab
    #pragma unroll
    for (int p = 0; p < 4; ++p) {
        int i = tid + p * 256;
        int d = i >> 4;                    // row (dim)
        int c = i & 15;                    // float4 chunk within row
        int v = v0 + (c << 2);
        const float* rowp = weight + (size_t)(d0 + d) * VOCAB;
        float4 w;
        if (v + 3 < VOCAB) {
            w = *reinterpret_cast<const float4*>(rowp + v);
        } else {
            w.x = (v + 0 < VOCAB) ? rowp[v + 0] : 0.f;
            w.y = (v + 1 < VOCAB) ? rowp[v + 1] : 0.f;
            w.z = (v + 2 < VOCAB) ? rowp[v + 2] : 0.f;
            w.w = (v + 3 < VOCAB) ? rowp[v + 3] : 0.f;
        }
        int cb = c << 2;                   // 2-way LDS write aliasing: free
        tile[d][cb + 0] = w.x;
        tile[d][cb + 1] = w.y;
        tile[d][cb + 2] = w.z;
        tile[d][cb + 3] = w.w;
    }
    __syncthreads();

    // write phase: 16 lanes x 4 dims per token -> float4 stores, 16 tokens in parallel
    int tl = tid >> 4;                     // token slot group 0..15
    int c4 = (tid & 15) << 2;              // dim offset within tile
    float4 b4 = *reinterpret_cast<const float4*>(bias + d0 + c4);
    int n = snn;
    for (int i = tl; i < n; i += 16) {
        unsigned e = slist[i];
        int vl = e & 63;
        size_t t = e >> 6;
        float4 o;
        o.x = tile[c4 + 0][vl] + b4.x;
        o.y = tile[c4 + 1][vl] + b4.y;
        o.z = tile[c4 + 2][vl] + b4.z;
        o.w = tile[c4 + 3][vl] + b4.w;
        *reinterpret_cast<float4*>(out + t * NUM_DIM + d0 + c4) = o;
    }
}

// ---------------- overflow fallback (n_ov == 0 for random tokens) ----------------

__global__ void __launch_bounds__(256) embed_overflow(
    const int* __restrict__ tokens, const float* __restrict__ weight,
    const float* __restrict__ bias, const int* __restrict__ n_ov,
    const int* __restrict__ ov_list, float* __restrict__ out)
{
    int n = *n_ov;
    for (int blk = blockIdx.x; blk < n; blk += gridDim.x) {
        int t = ov_list[blk];
        int v = tokens[t];
        int dd = threadIdx.x * 4;
        const float* wcol = weight + v;
        float4 b4 = *reinterpret_cast<const float4*>(bias + dd);
        float4 o;
        o.x = wcol[(size_t)(dd + 0) * VOCAB] + b4.x;
        o.y = wcol[(size_t)(dd + 1) * VOCAB] + b4.y;
        o.z = wcol[(size_t)(dd + 2) * VOCAB] + b4.z;
        o.w = wcol[(size_t)(dd + 3) * VOCAB] + b4.w;
        *reinterpret_cast<float4*>(out + (size_t)t * NUM_DIM + dd) = o;
    }
}

// ---------------- naive fallback if ws too small ----------------

__global__ void __launch_bounds__(256) token_embed_naive(
    const int* __restrict__ tokens, const float* __restrict__ weight,
    const float* __restrict__ bias, float* __restrict__ out, int n_tok)
{
    int t = blockIdx.x;
    if (t >= n_tok) return;
    int tok = tokens[t];
    int dd = threadIdx.x * 4;
    const float* wcol = weight + tok;
    float4 b4 = *reinterpret_cast<const float4*>(bias + dd);
    float4 o;
    o.x = wcol[(size_t)(dd + 0) * VOCAB] + b4.x;
    o.y = wcol[(size_t)(dd + 1) * VOCAB] + b4.y;
    o.z = wcol[(size_t)(dd + 2) * VOCAB] + b4.z;
    o.w = wcol[(size_t)(dd + 3) * VOCAB] + b4.w;
    *reinterpret_cast<float4*>(out + (size_t)t * NUM_DIM + dd) = o;
}

extern "C" void kernel_launch(void* const* d_in, const int* in_sizes, int n_in,
                              void* d_out, int out_size, void* d_ws, size_t ws_size,
                              hipStream_t stream)
{
    const int*   tokens = (const int*)d_in[0];
    const float* weight = (const float*)d_in[1];
    const float* bias   = (const float*)d_in[2];
    float*       out    = (float*)d_out;
    int n_tok = in_sizes[0];               // 16384

    // ws layout (ints): ccount[NVCH] | n_ov[64] | ov_list[n_tok] | clist[NVCH*CLCAP]
    size_t need_ints = (size_t)NVCH + 64 + (size_t)n_tok + (size_t)NVCH * CLCAP;
    if (ws_size < need_ints * sizeof(int)) {
        token_embed_naive<<<n_tok, 256, 0, stream>>>(tokens, weight, bias, out, n_tok);
        return;
    }

    int*      ccount  = (int*)d_ws;
    int*      n_ov    = ccount + NVCH;
    int*      ov_list = n_ov + 64;
    unsigned* clist   = (unsigned*)(ov_list + n_tok);

    init_kernel<<<(NVCH + 255) / 256, 256, 0, stream>>>(ccount, n_ov);
    scatter_kernel<<<(n_tok + 255) / 256, 256, 0, stream>>>(
        tokens, n_tok, ccount, clist, n_ov, ov_list);

    dim3 grid(NVCH, NUM_DIM / DB);         // (786, 16)
    embed_main<<<grid, 256, 0, stream>>>(weight, bias, ccount, clist, out);

    embed_overflow<<<64, 256, 0, stream>>>(tokens, weight, bias, n_ov, ov_list, out);
}

// Round 5
// 64.546 us; speedup vs baseline: 4.9158x; 1.1412x over previous
//
#include <hip/hip_runtime.h>
#include <hip/hip_bf16.h>

#define VOCAB   50257
#define NUM_DIM 1024
#define VB 64                              // vocab entries per tile
#define DB 64                              // dims per tile
#define NVCH ((VOCAB + VB - 1) / VB)       // 786 vocab chunks
#define CLCAP 96                           // list capacity per chunk (mean ~21)

typedef float f32x4 __attribute__((ext_vector_type(4)));  // NT-store-compatible

// ---------------- scatter: bucket tokens by vocab chunk ----------------

__global__ void __launch_bounds__(256) scatter_kernel(
    const int* __restrict__ tokens, int n_tok,
    int* ccount, unsigned* clist, int* n_ov, int* ov_list)
{
    int i = blockIdx.x * 256 + threadIdx.x;
    if (i >= n_tok) return;
    int v = tokens[i];
    int ch = v >> 6;                                   // vocab chunk (VB=64)
    int slot = atomicAdd(&ccount[ch], 1);
    if (slot < CLCAP) clist[(size_t)ch * CLCAP + slot] = ((unsigned)i << 6) | (unsigned)(v & 63);
    else { int p = atomicAdd(n_ov, 1); ov_list[p] = i; }
}

// ---------------- main: stream weight once, scatter to output rows ----------------
// grid(NUM_DIM/DB, NVCH): d-chunk is the FAST dispatch axis, so the 16 blocks
// that complete one token set's full 4KB rows run temporally adjacent
// (HBM page locality on the scattered writes) and share clist in cache.

__global__ void __launch_bounds__(256) embed_main(
    const float* __restrict__ weight, const float* __restrict__ bias,
    const int* __restrict__ ccount, const unsigned* __restrict__ clist,
    float* __restrict__ out)
{
    __shared__ float tile[DB][VB + 1];     // stride 65: column reads conflict-free
    __shared__ unsigned slist[CLCAP];
    __shared__ int snn;

    int tid = threadIdx.x;
    int cv = blockIdx.y;
    int v0 = cv * VB;
    int d0 = blockIdx.x * DB;

    if (tid == 0) {
        int c = ccount[cv];
        snn = c < CLCAP ? c : CLCAP;
    }
    if (tid < CLCAP) slist[tid] = clist[(size_t)cv * CLCAP + tid];

    // tile load: 64 rows x 16 float4-chunks; coalesced along vocab
    #pragma unroll
    for (int p = 0; p < 4; ++p) {
        int i = tid + p * 256;
        int d = i >> 4;                    // row (dim)
        int c = i & 15;                    // float4 chunk within row
        int v = v0 + (c << 2);
        const float* rowp = weight + (size_t)(d0 + d) * VOCAB;
        float4 w;
        if (v + 3 < VOCAB) {
            w = *reinterpret_cast<const float4*>(rowp + v);
        } else {
            w.x = (v + 0 < VOCAB) ? rowp[v + 0] : 0.f;
            w.y = (v + 1 < VOCAB) ? rowp[v + 1] : 0.f;
            w.z = (v + 2 < VOCAB) ? rowp[v + 2] : 0.f;
            w.w = (v + 3 < VOCAB) ? rowp[v + 3] : 0.f;
        }
        int cb = c << 2;                   // 2-way LDS write aliasing: free
        tile[d][cb + 0] = w.x;
        tile[d][cb + 1] = w.y;
        tile[d][cb + 2] = w.z;
        tile[d][cb + 3] = w.w;
    }
    __syncthreads();

    // write phase: 16 lanes x 4 dims per token -> float4 NT stores, 16 tokens parallel
    int tl = tid >> 4;                     // token slot group 0..15
    int c4 = (tid & 15) << 2;              // dim offset within tile
    float4 b4 = *reinterpret_cast<const float4*>(bias + d0 + c4);
    int n = snn;
    for (int i = tl; i < n; i += 16) {
        unsigned e = slist[i];
        int vl = e & 63;
        size_t t = e >> 6;
        f32x4 o;
        o.x = tile[c4 + 0][vl] + b4.x;
        o.y = tile[c4 + 1][vl] + b4.y;
        o.z = tile[c4 + 2][vl] + b4.z;
        o.w = tile[c4 + 3][vl] + b4.w;
        // non-temporal: out is write-once -> don't evict weight from L3
        __builtin_nontemporal_store(o, reinterpret_cast<f32x4*>(out + t * NUM_DIM + d0 + c4));
    }
}

// ---------------- overflow fallback (n_ov == 0 for random tokens) ----------------

__global__ void __launch_bounds__(256) embed_overflow(
    const int* __restrict__ tokens, const float* __restrict__ weight,
    const float* __restrict__ bias, const int* __restrict__ n_ov,
    const int* __restrict__ ov_list, float* __restrict__ out)
{
    int n = *n_ov;
    for (int blk = blockIdx.x; blk < n; blk += gridDim.x) {
        int t = ov_list[blk];
        int v = tokens[t];
        int dd = threadIdx.x * 4;
        const float* wcol = weight + v;
        float4 b4 = *reinterpret_cast<const float4*>(bias + dd);
        f32x4 o;
        o.x = wcol[(size_t)(dd + 0) * VOCAB] + b4.x;
        o.y = wcol[(size_t)(dd + 1) * VOCAB] + b4.y;
        o.z = wcol[(size_t)(dd + 2) * VOCAB] + b4.z;
        o.w = wcol[(size_t)(dd + 3) * VOCAB] + b4.w;
        __builtin_nontemporal_store(o, reinterpret_cast<f32x4*>(out + (size_t)t * NUM_DIM + dd));
    }
}

// ---------------- naive fallback if ws too small ----------------

__global__ void __launch_bounds__(256) token_embed_naive(
    const int* __restrict__ tokens, const float* __restrict__ weight,
    const float* __restrict__ bias, float* __restrict__ out, int n_tok)
{
    int t = blockIdx.x;
    if (t >= n_tok) return;
    int tok = tokens[t];
    int dd = threadIdx.x * 4;
    const float* wcol = weight + tok;
    float4 b4 = *reinterpret_cast<const float4*>(bias + dd);
    float4 o;
    o.x = wcol[(size_t)(dd + 0) * VOCAB] + b4.x;
    o.y = wcol[(size_t)(dd + 1) * VOCAB] + b4.y;
    o.z = wcol[(size_t)(dd + 2) * VOCAB] + b4.z;
    o.w = wcol[(size_t)(dd + 3) * VOCAB] + b4.w;
    *reinterpret_cast<float4*>(out + (size_t)t * NUM_DIM + dd) = o;
}

extern "C" void kernel_launch(void* const* d_in, const int* in_sizes, int n_in,
                              void* d_out, int out_size, void* d_ws, size_t ws_size,
                              hipStream_t stream)
{
    const int*   tokens = (const int*)d_in[0];
    const float* weight = (const float*)d_in[1];
    const float* bias   = (const float*)d_in[2];
    float*       out    = (float*)d_out;
    int n_tok = in_sizes[0];               // 16384

    // ws layout (ints): ccount[NVCH] | n_ov[64] | ov_list[n_tok] | clist[NVCH*CLCAP]
    size_t need_ints = (size_t)NVCH + 64 + (size_t)n_tok + (size_t)NVCH * CLCAP;
    if (ws_size < need_ints * sizeof(int)) {
        token_embed_naive<<<n_tok, 256, 0, stream>>>(tokens, weight, bias, out, n_tok);
        return;
    }

    int*      ccount  = (int*)d_ws;
    int*      n_ov    = ccount + NVCH;
    int*      ov_list = n_ov + 64;
    unsigned* clist   = (unsigned*)(ov_list + n_tok);

    // zero ccount + n_ov in one capturable memset (they are adjacent)
    (void)hipMemsetAsync(ccount, 0, (size_t)(NVCH + 64) * sizeof(int), stream);

    scatter_kernel<<<(n_tok + 255) / 256, 256, 0, stream>>>(
        tokens, n_tok, ccount, clist, n_ov, ov_list);

    dim3 grid(NUM_DIM / DB, NVCH);         // (16, 786): d-chunk fast axis
    embed_main<<<grid, 256, 0, stream>>>(weight, bias, ccount, clist, out);

    embed_overflow<<<16, 256, 0, stream>>>(tokens, weight, bias, n_ov, ov_list, out);
}